// Round 16
// baseline (484.833 us; speedup 1.0000x reference)
//
#include <hip/hip_runtime.h>
#include <hip/hip_fp16.h>
#include <hip/hip_cooperative_groups.h>

namespace cg = cooperative_groups;

// ---------------------------------------------------------------------------
// SimpleGCN: 2x GCNConv (self-loops, symmetric norm) + mean pool + MLP head
// N=100000 nodes, E=1.6M edges, IN=128, HID=64, G=128 graphs, NCLS=10
//
// Round 15: kernel-sum ~150us vs dur 200us -> ~50us of launch boundaries.
// Fuse the whole CSR build + mm1 into ONE cooperative kernel (512 blocks x
// 256 thr, trivially co-resident) with grid.sync() between phases:
//   prepW||hist -> scanA -> scanB -> partB -> csrC -> mm1
// Each phase keeps its R15 active-block count (hist/partB: 256 partitions,
// per R8's L2 write-amplification constraint; csrC: 391 buckets; mm1:
// grid-stride 1563 tiles). Launches 11 -> 6. Aggregate/mm2/pool unchanged.
// ---------------------------------------------------------------------------

#define TPB 256
#define FIX_SCALE 16777216.0f   // 2^24
#define BKT_BITS 8              // bucket = 256 nodes
#define PART_BLOCKS 256         // partition count (hist/partB)
#define BUILD_BLOCKS 512        // cooperative grid

typedef _Float16 f16x8 __attribute__((ext_vector_type(8)));
typedef float f32x4 __attribute__((ext_vector_type(4)));

__device__ __forceinline__ int lower_bound_i(const int* __restrict__ a, int n, int key) {
    int lo = 0, hi = n;
    while (lo < hi) {
        int mid = (lo + hi) >> 1;
        if (a[mid] < key) lo = mid + 1; else hi = mid;
    }
    return lo;
}

// --- MFMA matmul body: Hh[n,64] = dinv (.) (X[n,KK] @ W[KK,64]), fp16 out ---
template <int KK, bool FP32IN>
__device__ __forceinline__ void mm_body(const void* __restrict__ Xv,
                                        const __half* __restrict__ Wt,
                                        const float* __restrict__ dinv,
                                        __half* __restrict__ Hh, int n,
                                        int bid, int tid) {
    const int l = tid & 63;
    const int w = tid >> 6;
    const int rowBase = bid * 64 + w * 16;
    const int r = l & 15;
    const int q = l >> 4;
    const int arow = rowBase + r;
    const bool rv = arow < n;

    f32x4 acc[4] = {{0.f, 0.f, 0.f, 0.f}, {0.f, 0.f, 0.f, 0.f},
                    {0.f, 0.f, 0.f, 0.f}, {0.f, 0.f, 0.f, 0.f}};

#pragma unroll
    for (int k0 = 0; k0 < KK; k0 += 32) {
        f16x8 a = {};
        if (rv) {
            if constexpr (FP32IN) {
                const float* X = (const float*)Xv;
                const float4 x0 = *reinterpret_cast<const float4*>(&X[(size_t)arow * KK + k0 + 8 * q]);
                const float4 x1 = *reinterpret_cast<const float4*>(&X[(size_t)arow * KK + k0 + 8 * q + 4]);
                a[0] = (_Float16)x0.x; a[1] = (_Float16)x0.y;
                a[2] = (_Float16)x0.z; a[3] = (_Float16)x0.w;
                a[4] = (_Float16)x1.x; a[5] = (_Float16)x1.y;
                a[6] = (_Float16)x1.z; a[7] = (_Float16)x1.w;
            } else {
                const _Float16* X = (const _Float16*)Xv;
                a = *reinterpret_cast<const f16x8*>(&X[(size_t)arow * KK + k0 + 8 * q]);
            }
        }
#pragma unroll
        for (int ct = 0; ct < 4; ct++) {
            const f16x8 b = *reinterpret_cast<const f16x8*>(
                &Wt[(size_t)(ct * 16 + r) * KK + k0 + 8 * q]);
            acc[ct] = __builtin_amdgcn_mfma_f32_16x16x32_f16(a, b, acc[ct], 0, 0, 0);
        }
    }

#pragma unroll
    for (int i = 0; i < 4; i++) {
        int r2 = rowBase + 4 * q + i;
        if (r2 < n) {
            float dv = dinv[r2];
#pragma unroll
            for (int ct = 0; ct < 4; ct++)
                Hh[(size_t)r2 * 64 + ct * 16 + r] = (__half)(acc[ct][i] * dv);
        }
    }
}

template <int KK, bool FP32IN>
__global__ __launch_bounds__(256) void k_matmul_mfma(const void* __restrict__ Xv,
                                                     const __half* __restrict__ Wt,
                                                     const float* __restrict__ dinv,
                                                     __half* __restrict__ Hh, int n) {
    mm_body<KK, FP32IN>(Xv, Wt, dinv, Hh, n, blockIdx.x, threadIdx.x);
}

// --- COOPERATIVE build: prepW||hist -> scanA -> scanB -> partB -> csrC -> mm1
__global__ __launch_bounds__(256) void k_build(
    const int* __restrict__ row, const int* __restrict__ col,
    const float* __restrict__ ew, int E, int CH, int K, int KB, int NB,
    int* __restrict__ bh, int* __restrict__ bsums, int* __restrict__ bhs,
    int* __restrict__ offs, int* __restrict__ cnt, float* __restrict__ dinv,
    int2* __restrict__ part2, int2* __restrict__ csr,
    const float* __restrict__ W1, const float* __restrict__ W2,
    __half* __restrict__ Wt1, __half* __restrict__ Wt2,
    const float* __restrict__ X, __half* __restrict__ Hh, int N, int gbmm) {
    cg::grid_group grid = cg::this_grid();
    __shared__ __align__(16) int smem[1024];   // 4KB, carved per phase
    const int b = blockIdx.x;
    const int t = threadIdx.x;

    // ---- phase 1: histogram (blocks 0..255) + W prep (block 256) ----------
    if (b == 256) {
        for (int i = t; i < 64 * 128; i += 256) {
            int c = i >> 7, k = i & 127;
            Wt1[i] = (__half)W1[k * 64 + c];
        }
        for (int i = t; i < 64 * 64; i += 256) {
            int c = i >> 6, k = i & 63;
            Wt2[i] = (__half)W2[k * 64 + c];
        }
    } else if (b < PART_BLOCKS) {
        int* hist = smem;
        for (int i = t; i < K; i += 256) hist[i] = 0;
        __syncthreads();
        int s = b * CH, e = min(E, s + CH);
        for (int i = s + t; i < e; i += 256) atomicAdd(&hist[col[i] >> BKT_BITS], 1);
        __syncthreads();
        for (int i = t; i < K; i += 256) bh[i * PART_BLOCKS + b] = hist[i];
    }
    grid.sync();

    // ---- phase 2: scanA — per-chunk totals (1024 elems/chunk) --------------
    if (b < NB) {
        int* red = smem;
        int base = b * 1024;
        int s = 0;
#pragma unroll
        for (int i = 0; i < 4; i++) {
            int idx = base + t + i * 256;
            if (idx < KB) s += bh[idx];
        }
#pragma unroll
        for (int off = 32; off > 0; off >>= 1) s += __shfl_down(s, off);
        if ((t & 63) == 0) red[t >> 6] = s;
        __syncthreads();
        if (t == 0) bsums[b] = red[0] + red[1] + red[2] + red[3];
    }
    grid.sync();

    // ---- phase 3: scanB — exclusive scan of bh into bhs --------------------
    if (b < NB) {
        int* ts = smem;
        int pre = (t < b) ? bsums[t] : 0;
        ts[t] = pre; __syncthreads();
        for (int off = 128; off > 0; off >>= 1) {
            if (t < off) ts[t] += ts[t + off];
            __syncthreads();
        }
        int boff = ts[0];
        __syncthreads();
        int base = b * 1024 + 4 * t;
        int v[4]; int s = 0;
#pragma unroll
        for (int i = 0; i < 4; i++) {
            int idx = base + i;
            v[i] = (idx < KB) ? bh[idx] : 0;
            s += v[i];
        }
        ts[t] = s; __syncthreads();
        for (int off = 1; off < 256; off <<= 1) {
            int x = (t >= off) ? ts[t - off] : 0;
            __syncthreads();
            ts[t] += x;
            __syncthreads();
        }
        int run = ts[t] - s + boff;
#pragma unroll
        for (int i = 0; i < 4; i++) {
            int idx = base + i;
            if (idx < KB) bhs[idx] = run;
            run += v[i];
        }
    }
    grid.sync();

    // ---- phase 4: partition edges by bucket (blocks 0..255) ----------------
    if (b < PART_BLOCKS) {
        int* cur = smem;
        for (int i = t; i < K; i += 256) cur[i] = bhs[i * PART_BLOCKS + b];
        __syncthreads();
        int s = b * CH, e = min(E, s + CH);
        for (int i = s + t; i < e; i += 256) {
            int c = col[i];
            int pos = atomicAdd(&cur[c >> BKT_BITS], 1);
            part2[pos] = make_int2(row[i] | ((c & 255) << 20), __float_as_int(ew[i]));
        }
    }
    grid.sync();

    // ---- phase 5: per-bucket CSR finalize (blocks 0..K-1) ------------------
    if (b < K) {
        int* lcnt = smem;
        unsigned* lew = (unsigned*)(smem + 256);
        int* lcur = smem + 512;
        int* ts = smem + 768;
        int n0 = b << BKT_BITS;
        lcnt[t] = 0; lew[t] = 0;
        __syncthreads();
        int estart = bhs[b * PART_BLOCKS];
        int eend   = (b + 1 < K) ? bhs[(b + 1) * PART_BLOCKS] : E;
        for (int i = estart + t; i < eend; i += 256) {
            int2 v = part2[i];
            int c = (v.x >> 20) & 255;
            atomicAdd(&lcnt[c], 1);
            float w = __int_as_float(v.y);
            atomicAdd(&lew[c], (unsigned)(w * FIX_SCALE + 0.5f));
        }
        __syncthreads();
        int myc = lcnt[t];
        ts[t] = myc; __syncthreads();
        for (int off = 1; off < 256; off <<= 1) {
            int x = (t >= off) ? ts[t - off] : 0;
            __syncthreads();
            ts[t] += x;
            __syncthreads();
        }
        int goff = estart + ts[t] - myc;
        int node = n0 + t;
        if (node < N) {
            offs[node] = goff;
            cnt[node]  = myc;
            float deg = 1.0f + (float)((double)lew[t] * (1.0 / 16777216.0));
            dinv[node] = 1.0f / sqrtf(deg);
        }
        lcur[t] = goff;
        __syncthreads();
        for (int i = estart + t; i < eend; i += 256) {
            int2 v = part2[i];
            int c = (v.x >> 20) & 255;
            int pos = atomicAdd(&lcur[c], 1);
            csr[pos] = make_int2(v.x & 0xFFFFF, v.y);
        }
    }
    grid.sync();

    // ---- phase 6: mm1 = fp16(dinv (.) (X @ W1)), grid-stride tiles ---------
    for (int tile = b; tile < gbmm; tile += (int)gridDim.x)
        mm_body<128, true>(X, Wt1, dinv, Hh, N, tile, t);
}

// --- aggregate: outh = fp16(relu(dinv[c]*(sum ew*h'[src] + h'[c]) + b)) -----
__global__ __launch_bounds__(256) void k_aggregate(
    const __half2* __restrict__ hp2, const int* __restrict__ offs,
    const int* __restrict__ cnt, const int2* __restrict__ csr,
    const float* __restrict__ dinv, const float* __restrict__ bias,
    __half2* __restrict__ outh, int n) {
    const int lane = threadIdx.x & 63;
    const int epar = lane >> 5;
    const int lpos = lane & 31;
    const int node = blockIdx.x * 4 + (threadIdx.x >> 6);
    if (node >= n) return;
    const int c = cnt[node];
    const int s = offs[node];

    int2 mc = make_int2(node, 0);
    if (lane < c) mc = csr[s + lane];
    const int cc = min(c, 64);
    const int npairs = (cc + 1) >> 1;
    const int p8 = (npairs + 7) & ~7;

    float ax[8] = {0.f, 0.f, 0.f, 0.f, 0.f, 0.f, 0.f, 0.f};
    float ay[8] = {0.f, 0.f, 0.f, 0.f, 0.f, 0.f, 0.f, 0.f};

    for (int p = 0; p < p8; p += 8) {
#pragma unroll
        for (int i = 0; i < 8; i++) {
            int idx = 2 * (p + i) + epar;
            int src = __shfl(mc.x, idx);
            float w = __int_as_float(__shfl(mc.y, idx));
            float2 f = __half22float2(hp2[(size_t)src * 32 + lpos]);
            ax[i] = fmaf(f.x, w, ax[i]);
            ay[i] = fmaf(f.y, w, ay[i]);
        }
    }
    float tx = ((ax[0] + ax[1]) + (ax[2] + ax[3])) + ((ax[4] + ax[5]) + (ax[6] + ax[7]));
    float ty = ((ay[0] + ay[1]) + (ay[2] + ay[3])) + ((ay[4] + ay[5]) + (ay[6] + ay[7]));
    tx += __shfl(tx, lane ^ 32);
    ty += __shfl(ty, lane ^ 32);

    for (int j = 64; j < c; ++j) {
        int2 e = csr[s + j];
        float2 f = __half22float2(hp2[(size_t)e.x * 32 + lpos]);
        float w = __int_as_float(e.y);
        tx = fmaf(f.x, w, tx);
        ty = fmaf(f.y, w, ty);
    }

    if (epar == 0) {
        float2 sv = __half22float2(hp2[(size_t)node * 32 + lpos]);
        const float2 bv = *reinterpret_cast<const float2*>(&bias[lpos * 2]);
        float dv = dinv[node];
        float rx = fmaxf(fmaf(tx + sv.x, dv, bv.x), 0.f);
        float ry = fmaxf(fmaf(ty + sv.y, dv, bv.y), 0.f);
        outh[(size_t)node * 32 + lpos] = __floats2half2_rn(rx, ry);
    }
}

// --- pool part 1: 4 blocks per graph, partial sums ---------------------------
__global__ __launch_bounds__(256) void k_pool4(
    const __half* __restrict__ oh, const int* __restrict__ batch, int n,
    float* __restrict__ psum) {
    const int g = blockIdx.x >> 2;
    const int sl = blockIdx.x & 3;
    const int t = threadIdx.x;
    const int lane = t & 63, w = t >> 6;
    __shared__ float sums[4][64];

    int start = lower_bound_i(batch, n, g);
    int end   = lower_bound_i(batch, n, g + 1);
    int len   = end - start;
    int s0 = start + (len * sl) / 4;
    int s1 = start + (len * (sl + 1)) / 4;

    float acc = 0.f;
    for (int i = s0 + w; i < s1; i += 4)
        acc += __half2float(oh[(size_t)i * 64 + lane]);
    sums[w][lane] = acc;
    __syncthreads();
    if (w == 0) {
        float v = sums[0][lane] + sums[1][lane] + sums[2][lane] + sums[3][lane];
        psum[(size_t)blockIdx.x * 64 + lane] = v;
    }
}

// --- pool part 2: combine + MLP head -----------------------------------------
__global__ __launch_bounds__(64) void k_head(
    const float* __restrict__ psum, const int* __restrict__ batch, int n,
    const float* __restrict__ Wc1, const float* __restrict__ bc1,
    const float* __restrict__ Wc2, const float* __restrict__ bc2,
    float* __restrict__ out) {
    const int g = blockIdx.x;
    const int t = threadIdx.x;
    __shared__ float pooled[64];
    __shared__ float z[32];

    int start = lower_bound_i(batch, n, g);
    int end   = lower_bound_i(batch, n, g + 1);
    float ccount = (float)(end - start);

    float v = psum[(size_t)(g * 4 + 0) * 64 + t] + psum[(size_t)(g * 4 + 1) * 64 + t] +
              psum[(size_t)(g * 4 + 2) * 64 + t] + psum[(size_t)(g * 4 + 3) * 64 + t];
    pooled[t] = v / fmaxf(ccount, 1.0f);
    __syncthreads();
    if (t < 32) {
        float a = bc1[t];
#pragma unroll
        for (int k = 0; k < 64; k++) a = fmaf(pooled[k], Wc1[k * 32 + t], a);
        z[t] = fmaxf(a, 0.f);
    }
    __syncthreads();
    if (t < 10) {
        float a = bc2[t];
#pragma unroll
        for (int k = 0; k < 32; k++) a = fmaf(z[k], Wc2[k * 10 + t], a);
        out[g * 10 + t] = a;
    }
}

// ---------------------------------------------------------------------------
extern "C" void kernel_launch(void* const* d_in, const int* in_sizes, int n_in,
                              void* d_out, int out_size, void* d_ws, size_t ws_size,
                              hipStream_t stream) {
    const float* x    = (const float*)d_in[0];
    const int*   ei   = (const int*)d_in[1];
    const float* ew   = (const float*)d_in[2];
    const int*   bat  = (const int*)d_in[3];
    const float* W1   = (const float*)d_in[4];
    const float* b1   = (const float*)d_in[5];
    const float* W2   = (const float*)d_in[6];
    const float* b2   = (const float*)d_in[7];
    const float* Wc1  = (const float*)d_in[8];
    const float* bc1  = (const float*)d_in[9];
    const float* Wc2  = (const float*)d_in[10];
    const float* bc2  = (const float*)d_in[11];
    float* out = (float*)d_out;

    const int N = in_sizes[0] / 128;
    const int E = in_sizes[2];
    const int G = out_size / 10;
    const int K = (N + 255) >> BKT_BITS;                 // buckets of 256 nodes
    const int KB = K * PART_BLOCKS;                      // histogram elements
    const int CH = (E + PART_BLOCKS - 1) / PART_BLOCKS;  // edges/partition block
    const int NB = (KB + 1023) / 1024;                   // scan chunks (<=256)

    const int* row = ei;
    const int* col = ei + E;

    // workspace carve-up (256B aligned slices)
    char* p = (char*)d_ws;
    auto alloc = [&](size_t bytes) -> void* {
        void* r = (void*)p;
        p += (bytes + 255) & ~(size_t)255;
        return r;
    };
    int*    bh    = (int*)   alloc((size_t)KB * 4);
    int*    bsums = (int*)   alloc(8192);
    int*    bhs   = (int*)   alloc((size_t)KB * 4);
    int*    offs  = (int*)   alloc((size_t)N * 4);
    int*    cnt   = (int*)   alloc((size_t)N * 4);
    float*  dinv  = (float*) alloc((size_t)N * 4);
    __half* Wt1   = (__half*)alloc(64 * 128 * 2);
    __half* Wt2   = (__half*)alloc(64 * 64 * 2);
    float*  psum  = (float*) alloc((size_t)G * 4 * 64 * 4);
    int2*   csr   = (int2*)  alloc((size_t)E * 8);
    // fp16 h aliases the partition array (part2 consumed in phase 5, h
    // written in phase 6 — safe: phases separated by grid.sync)
    size_t hbytes = (size_t)N * 64 * 2;
    size_t pbytes = (size_t)E * 8;
    char*   hbase = (char*)  alloc(hbytes > pbytes ? hbytes : pbytes);
    __half* o     = (__half*)alloc((size_t)N * 64 * 2);
    int2*   part2 = (int2*)  hbase;
    __half* h     = (__half*)hbase;

    const int gb_mm = (N + 63) / 64;
    const int gb_ag = (N + 3) / 4;

    // 1. cooperative build: prepW||hist -> scan -> partB -> csrC -> mm1
    {
        int gbmm = gb_mm;
        void* args[] = {
            (void*)&row, (void*)&col, (void*)&ew, (void*)&E, (void*)&CH,
            (void*)&K, (void*)&KB, (void*)&NB,
            (void*)&bh, (void*)&bsums, (void*)&bhs,
            (void*)&offs, (void*)&cnt, (void*)&dinv,
            (void*)&part2, (void*)&csr,
            (void*)&W1, (void*)&W2, (void*)&Wt1, (void*)&Wt2,
            (void*)&x, (void*)&h, (void*)&N, (void*)&gbmm};
        hipLaunchCooperativeKernel((void*)k_build, dim3(BUILD_BLOCKS), dim3(256),
                                   args, 0, stream);
    }
    // 2. layer-1 aggregate
    k_aggregate<<<gb_ag, 256, 0, stream>>>((const __half2*)h, offs, cnt, csr, dinv, b1,
                                           (__half2*)o, N);
    // 3. layer-2 matmul
    k_matmul_mfma<64, false><<<gb_mm, 256, 0, stream>>>(o, Wt2, dinv, h, N);
    // 4. layer-2 aggregate
    k_aggregate<<<gb_ag, 256, 0, stream>>>((const __half2*)h, offs, cnt, csr, dinv, b2,
                                           (__half2*)o, N);
    // 5-6. pool + head
    k_pool4<<<G * 4, 256, 0, stream>>>(o, bat, N, psum);
    k_head<<<G, 64, 0, stream>>>(psum, bat, N, Wc1, bc1, Wc2, bc2, out);
}

// Round 17
// 198.795 us; speedup vs baseline: 2.4389x; 2.4389x over previous
//
#include <hip/hip_runtime.h>
#include <hip/hip_fp16.h>

// ---------------------------------------------------------------------------
// SimpleGCN: 2x GCNConv (self-loops, symmetric norm) + mean pool + MLP head
// N=100000 nodes, E=1.6M edges, IN=128, HID=64, G=128 graphs, NCLS=10
//
// Round 16: REVERT to the R14/R15 measured-good 11-launch structure
// (200.5us). R15's cooperative fusion regressed 2.4x: each grid.sync()
// across 512 blocks costs ~60us on 8-XCD MI355X (device-scope drain across
// non-coherent L2s; k_build spent ~80% of 360us in sync spin). Both
// chain-compression strategies (R13 same-launch mixing, R15 coop phases)
// are falsified; serialized launches are cheaper than grid-wide sync.
//
// Floor budget: agg 2x40us (structural cross-XCD gather broadcast at
// random-line service rate; 4 instruction-mix variants all pinned), CSR
// build ~45us streaming, MFMA matmuls ~20us memory-bound, pool ~8us,
// ~45us launch overhead.
// ---------------------------------------------------------------------------

#define TPB 256
#define FIX_SCALE 16777216.0f   // 2^24
#define BKT_BITS 8              // bucket = 256 nodes
#define PART_BLOCKS 256         // blocks in hist/partition passes

typedef _Float16 f16x8 __attribute__((ext_vector_type(8)));
typedef float f32x4 __attribute__((ext_vector_type(4)));

__device__ __forceinline__ int lower_bound_i(const int* __restrict__ a, int n, int key) {
    int lo = 0, hi = n;
    while (lo < hi) {
        int mid = (lo + hi) >> 1;
        if (a[mid] < key) lo = mid + 1; else hi = mid;
    }
    return lo;
}

// --- A. per-block bucket histogram (+ fused W prep on block 0) ---------------
__global__ __launch_bounds__(256) void k_histA(const int* __restrict__ col, int E, int CH,
                                               int K, int* __restrict__ bh,
                                               const float* __restrict__ W1,
                                               const float* __restrict__ W2,
                                               __half* __restrict__ Wt1,
                                               __half* __restrict__ Wt2) {
    __shared__ int hist[512];
    int b = blockIdx.x, t = threadIdx.x;
    if (b == 0) {   // W transpose + fp16 convert: Wt[c][k] = W[k][c]
        for (int i = t; i < 64 * 128; i += 256) {
            int c = i >> 7, k = i & 127;
            Wt1[i] = (__half)W1[k * 64 + c];
        }
        for (int i = t; i < 64 * 64; i += 256) {
            int c = i >> 6, k = i & 63;
            Wt2[i] = (__half)W2[k * 64 + c];
        }
    }
    for (int i = t; i < K; i += 256) hist[i] = 0;
    __syncthreads();
    int s = b * CH, e = min(E, s + CH);
    for (int i = s + t; i < e; i += 256) atomicAdd(&hist[col[i] >> BKT_BITS], 1);
    __syncthreads();
    for (int i = t; i < K; i += 256) bh[i * PART_BLOCKS + b] = hist[i];
}

// --- scan part 1: per-block totals (1024 elems per block) --------------------
__global__ void k_scan_partial(const int* __restrict__ cnt, int* __restrict__ bsums, int n) {
    __shared__ int red[4];
    int b = blockIdx.x, t = threadIdx.x;
    int base = b * 1024;
    int s = 0;
#pragma unroll
    for (int i = 0; i < 4; i++) {
        int idx = base + t + i * TPB;
        if (idx < n) s += cnt[idx];
    }
#pragma unroll
    for (int off = 32; off > 0; off >>= 1) s += __shfl_down(s, off);
    if ((t & 63) == 0) red[t >> 6] = s;
    __syncthreads();
    if (t == 0) bsums[b] = red[0] + red[1] + red[2] + red[3];
}

// --- scan part 2: self-scan bsums (<=256) + chunk exclusive scan -------------
__global__ void k_scan_final2(const int* __restrict__ cnt, const int* __restrict__ bsums,
                              int* __restrict__ offs, int n, int nb) {
    __shared__ int ts[TPB];
    int b = blockIdx.x, t = threadIdx.x;
    // prefix of preceding block totals (b <= 255)
    int pre = (t < b) ? bsums[t] : 0;
    ts[t] = pre; __syncthreads();
    for (int off = 128; off > 0; off >>= 1) {
        if (t < off) ts[t] += ts[t + off];
        __syncthreads();
    }
    int boff = ts[0];
    __syncthreads();

    int base = b * 1024 + 4 * t;
    int v[4]; int s = 0;
#pragma unroll
    for (int i = 0; i < 4; i++) {
        int idx = base + i;
        v[i] = (idx < n) ? cnt[idx] : 0;
        s += v[i];
    }
    ts[t] = s; __syncthreads();
    for (int off = 1; off < 256; off <<= 1) {
        int x = (t >= off) ? ts[t - off] : 0;
        __syncthreads();
        ts[t] += x;
        __syncthreads();
    }
    int run = ts[t] - s + boff;
#pragma unroll
    for (int i = 0; i < 4; i++) {
        int idx = base + i;
        if (idx < n) offs[idx] = run;
        run += v[i];
    }
}

// --- C. partition edges by bucket (LDS cursors; packed 8B record) -----------
__global__ __launch_bounds__(256) void k_partB(const int* __restrict__ row,
                                               const int* __restrict__ col,
                                               const float* __restrict__ ew,
                                               const int* __restrict__ bhs,
                                               int E, int CH, int K,
                                               int2* __restrict__ part2) {
    __shared__ int cur[512];
    int b = blockIdx.x, t = threadIdx.x;
    for (int i = t; i < K; i += 256) cur[i] = bhs[i * PART_BLOCKS + b];
    __syncthreads();
    int s = b * CH, e = min(E, s + CH);
    for (int i = s + t; i < e; i += 256) {
        int c = col[i];
        int pos = atomicAdd(&cur[c >> BKT_BITS], 1);
        part2[pos] = make_int2(row[i] | ((c & 255) << 20), __float_as_int(ew[i]));
    }
}

// --- D. per-bucket CSR finalize ----------------------------------------------
__global__ __launch_bounds__(256) void k_csrC(const int2* __restrict__ part2,
                                              const int* __restrict__ bhs,
                                              int K, int N, int E,
                                              int* __restrict__ offs, int* __restrict__ cnt,
                                              float* __restrict__ dinv,
                                              int2* __restrict__ csr) {
    __shared__ int lcnt[256];
    __shared__ unsigned lew[256];
    __shared__ int lcur[256];
    __shared__ int ts[256];
    int k = blockIdx.x, t = threadIdx.x;
    int n0 = k << BKT_BITS;
    lcnt[t] = 0; lew[t] = 0;
    __syncthreads();
    int estart = bhs[k * PART_BLOCKS];
    int eend   = (k + 1 < K) ? bhs[(k + 1) * PART_BLOCKS] : E;
    for (int i = estart + t; i < eend; i += 256) {
        int2 v = part2[i];
        int c = (v.x >> 20) & 255;
        atomicAdd(&lcnt[c], 1);
        float w = __int_as_float(v.y);
        atomicAdd(&lew[c], (unsigned)(w * FIX_SCALE + 0.5f));
    }
    __syncthreads();
    int myc = lcnt[t];
    ts[t] = myc; __syncthreads();
    for (int off = 1; off < 256; off <<= 1) {
        int x = (t >= off) ? ts[t - off] : 0;
        __syncthreads();
        ts[t] += x;
        __syncthreads();
    }
    int goff = estart + ts[t] - myc;   // global CSR offset for node n0+t
    int node = n0 + t;
    if (node < N) {
        offs[node] = goff;
        cnt[node]  = myc;
        float deg = 1.0f + (float)((double)lew[t] * (1.0 / 16777216.0));
        dinv[node] = 1.0f / sqrtf(deg);
    }
    lcur[t] = goff;
    __syncthreads();
    for (int i = estart + t; i < eend; i += 256) {
        int2 v = part2[i];
        int c = (v.x >> 20) & 255;
        int pos = atomicAdd(&lcur[c], 1);
        csr[pos] = make_int2(v.x & 0xFFFFF, v.y);
    }
}

// --- MFMA matmul: Hh[n,64] (fp16) = dinv (.) (X[n,K] @ W[K,64]) -------------
// FP32IN selects A-frag source: fp32 X (cvt) or fp16 X (direct 16B load).
template <int K, bool FP32IN>
__global__ __launch_bounds__(256) void k_matmul_mfma(const void* __restrict__ Xv,
                                                     const __half* __restrict__ Wt,
                                                     const float* __restrict__ dinv,
                                                     __half* __restrict__ Hh, int n) {
    const int l = threadIdx.x & 63;
    const int w = threadIdx.x >> 6;
    const int rowBase = blockIdx.x * 64 + w * 16;
    const int r = l & 15;
    const int q = l >> 4;
    const int arow = rowBase + r;
    const bool rv = arow < n;

    f32x4 acc[4] = {{0.f, 0.f, 0.f, 0.f}, {0.f, 0.f, 0.f, 0.f},
                    {0.f, 0.f, 0.f, 0.f}, {0.f, 0.f, 0.f, 0.f}};

#pragma unroll
    for (int k0 = 0; k0 < K; k0 += 32) {
        f16x8 a = {};
        if (rv) {
            if constexpr (FP32IN) {
                const float* X = (const float*)Xv;
                const float4 x0 = *reinterpret_cast<const float4*>(&X[(size_t)arow * K + k0 + 8 * q]);
                const float4 x1 = *reinterpret_cast<const float4*>(&X[(size_t)arow * K + k0 + 8 * q + 4]);
                a[0] = (_Float16)x0.x; a[1] = (_Float16)x0.y;
                a[2] = (_Float16)x0.z; a[3] = (_Float16)x0.w;
                a[4] = (_Float16)x1.x; a[5] = (_Float16)x1.y;
                a[6] = (_Float16)x1.z; a[7] = (_Float16)x1.w;
            } else {
                const _Float16* X = (const _Float16*)Xv;
                a = *reinterpret_cast<const f16x8*>(&X[(size_t)arow * K + k0 + 8 * q]);
            }
        }
#pragma unroll
        for (int ct = 0; ct < 4; ct++) {
            const f16x8 b = *reinterpret_cast<const f16x8*>(
                &Wt[(size_t)(ct * 16 + r) * K + k0 + 8 * q]);
            acc[ct] = __builtin_amdgcn_mfma_f32_16x16x32_f16(a, b, acc[ct], 0, 0, 0);
        }
    }

#pragma unroll
    for (int i = 0; i < 4; i++) {
        int r2 = rowBase + 4 * q + i;
        if (r2 < n) {
            float dv = dinv[r2];
#pragma unroll
            for (int ct = 0; ct < 4; ct++)
                Hh[(size_t)r2 * 64 + ct * 16 + r] = (__half)(acc[ct][i] * dv);
        }
    }
}

// --- aggregate: outh = fp16(relu(dinv[c]*(sum ew*h'[src] + h'[c]) + b)) -----
// hp is fp16 [N][64] = one 128B line per row. Wave per node; lanes =
// 2 edge-parities x 32 channel-pairs (half2). One wave-wide load = two
// edges' rows; 8 accumulator pairs = 16 edges in flight. Accumulate fp32.
__global__ __launch_bounds__(256) void k_aggregate(
    const __half2* __restrict__ hp2, const int* __restrict__ offs,
    const int* __restrict__ cnt, const int2* __restrict__ csr,
    const float* __restrict__ dinv, const float* __restrict__ bias,
    __half2* __restrict__ outh, int n) {
    const int lane = threadIdx.x & 63;
    const int epar = lane >> 5;          // which edge of the pair
    const int lpos = lane & 31;          // channel-pair index (2 ch per lane)
    const int node = blockIdx.x * 4 + (threadIdx.x >> 6);
    if (node >= n) return;
    const int c = cnt[node];
    const int s = offs[node];

    // stage up to 64 CSR entries across lanes; pad = (self, 0.0) -> no-op
    int2 mc = make_int2(node, 0);
    if (lane < c) mc = csr[s + lane];
    const int cc = min(c, 64);
    const int npairs = (cc + 1) >> 1;
    const int p8 = (npairs + 7) & ~7;

    float ax[8] = {0.f, 0.f, 0.f, 0.f, 0.f, 0.f, 0.f, 0.f};
    float ay[8] = {0.f, 0.f, 0.f, 0.f, 0.f, 0.f, 0.f, 0.f};

    for (int p = 0; p < p8; p += 8) {
#pragma unroll
        for (int i = 0; i < 8; i++) {
            int idx = 2 * (p + i) + epar;          // per-half edge index (<=63)
            int src = __shfl(mc.x, idx);
            float w = __int_as_float(__shfl(mc.y, idx));
            float2 f = __half22float2(hp2[(size_t)src * 32 + lpos]);
            ax[i] = fmaf(f.x, w, ax[i]);
            ay[i] = fmaf(f.y, w, ay[i]);
        }
    }
    // reduce 8 accumulators, then combine edge parities
    float tx = ((ax[0] + ax[1]) + (ax[2] + ax[3])) + ((ax[4] + ax[5]) + (ax[6] + ax[7]));
    float ty = ((ay[0] + ay[1]) + (ay[2] + ay[3])) + ((ay[4] + ay[5]) + (ay[6] + ay[7]));
    tx += __shfl(tx, lane ^ 32);
    ty += __shfl(ty, lane ^ 32);

    // rare overflow (deg > 64): uniform csr read
    for (int j = 64; j < c; ++j) {
        int2 e = csr[s + j];
        float2 f = __half22float2(hp2[(size_t)e.x * 32 + lpos]);
        float w = __int_as_float(e.y);
        tx = fmaf(f.x, w, tx);
        ty = fmaf(f.y, w, ty);
    }

    if (epar == 0) {
        float2 sv = __half22float2(hp2[(size_t)node * 32 + lpos]);
        const float2 bv = *reinterpret_cast<const float2*>(&bias[lpos * 2]);
        float dv = dinv[node];
        float rx = fmaxf(fmaf(tx + sv.x, dv, bv.x), 0.f);
        float ry = fmaxf(fmaf(ty + sv.y, dv, bv.y), 0.f);
        outh[(size_t)node * 32 + lpos] = __floats2half2_rn(rx, ry);
    }
}

// --- pool part 1: 4 blocks per graph, partial sums ---------------------------
__global__ __launch_bounds__(256) void k_pool4(
    const __half* __restrict__ oh, const int* __restrict__ batch, int n,
    float* __restrict__ psum) {
    const int g = blockIdx.x >> 2;
    const int sl = blockIdx.x & 3;
    const int t = threadIdx.x;
    const int lane = t & 63, w = t >> 6;   // 4 waves
    __shared__ float sums[4][64];

    int start = lower_bound_i(batch, n, g);
    int end   = lower_bound_i(batch, n, g + 1);
    int len   = end - start;
    int s0 = start + (len * sl) / 4;
    int s1 = start + (len * (sl + 1)) / 4;

    float acc = 0.f;
    for (int i = s0 + w; i < s1; i += 4)
        acc += __half2float(oh[(size_t)i * 64 + lane]);
    sums[w][lane] = acc;
    __syncthreads();
    if (w == 0) {
        float v = sums[0][lane] + sums[1][lane] + sums[2][lane] + sums[3][lane];
        psum[(size_t)blockIdx.x * 64 + lane] = v;
    }
}

// --- pool part 2: combine + MLP head -----------------------------------------
__global__ __launch_bounds__(64) void k_head(
    const float* __restrict__ psum, const int* __restrict__ batch, int n,
    const float* __restrict__ Wc1, const float* __restrict__ bc1,
    const float* __restrict__ Wc2, const float* __restrict__ bc2,
    float* __restrict__ out) {
    const int g = blockIdx.x;
    const int t = threadIdx.x;   // 64 threads
    __shared__ float pooled[64];
    __shared__ float z[32];

    int start = lower_bound_i(batch, n, g);
    int end   = lower_bound_i(batch, n, g + 1);
    float ccount = (float)(end - start);

    float v = psum[(size_t)(g * 4 + 0) * 64 + t] + psum[(size_t)(g * 4 + 1) * 64 + t] +
              psum[(size_t)(g * 4 + 2) * 64 + t] + psum[(size_t)(g * 4 + 3) * 64 + t];
    pooled[t] = v / fmaxf(ccount, 1.0f);
    __syncthreads();
    if (t < 32) {
        float a = bc1[t];
#pragma unroll
        for (int k = 0; k < 64; k++) a = fmaf(pooled[k], Wc1[k * 32 + t], a);
        z[t] = fmaxf(a, 0.f);
    }
    __syncthreads();
    if (t < 10) {
        float a = bc2[t];
#pragma unroll
        for (int k = 0; k < 32; k++) a = fmaf(z[k], Wc2[k * 10 + t], a);
        out[g * 10 + t] = a;
    }
}

// ---------------------------------------------------------------------------
extern "C" void kernel_launch(void* const* d_in, const int* in_sizes, int n_in,
                              void* d_out, int out_size, void* d_ws, size_t ws_size,
                              hipStream_t stream) {
    const float* x    = (const float*)d_in[0];
    const int*   ei   = (const int*)d_in[1];
    const float* ew   = (const float*)d_in[2];
    const int*   bat  = (const int*)d_in[3];
    const float* W1   = (const float*)d_in[4];
    const float* b1   = (const float*)d_in[5];
    const float* W2   = (const float*)d_in[6];
    const float* b2   = (const float*)d_in[7];
    const float* Wc1  = (const float*)d_in[8];
    const float* bc1  = (const float*)d_in[9];
    const float* Wc2  = (const float*)d_in[10];
    const float* bc2  = (const float*)d_in[11];
    float* out = (float*)d_out;

    const int N = in_sizes[0] / 128;
    const int E = in_sizes[2];
    const int G = out_size / 10;
    const int K = (N + 255) >> BKT_BITS;          // buckets of 256 nodes
    const int KB = K * PART_BLOCKS;               // histogram elements
    const int CH = (E + PART_BLOCKS - 1) / PART_BLOCKS;  // edges per partition block

    const int* row = ei;
    const int* col = ei + E;

    // workspace carve-up (256B aligned slices)
    char* p = (char*)d_ws;
    auto alloc = [&](size_t bytes) -> void* {
        void* r = (void*)p;
        p += (bytes + 255) & ~(size_t)255;
        return r;
    };
    int*    bh    = (int*)   alloc((size_t)KB * 4);
    int*    bhs   = (int*)   alloc((size_t)KB * 4);
    int*    bsums = (int*)   alloc(8192);
    int*    offs  = (int*)   alloc((size_t)N * 4);
    int*    cnt   = (int*)   alloc((size_t)N * 4);
    float*  dinv  = (float*) alloc((size_t)N * 4);
    __half* Wt1   = (__half*)alloc(64 * 128 * 2);
    __half* Wt2   = (__half*)alloc(64 * 64 * 2);
    float*  psum  = (float*) alloc((size_t)G * 4 * 64 * 4);
    int2*   csr   = (int2*)  alloc((size_t)E * 8);
    // fp16 h aliases the partition array (part2 dead before mm1 runs)
    size_t hbytes = (size_t)N * 64 * 2;
    size_t pbytes = (size_t)E * 8;
    char*   hbase = (char*)  alloc(hbytes > pbytes ? hbytes : pbytes);
    __half* o     = (__half*)alloc((size_t)N * 64 * 2);
    int2*   part2 = (int2*)  hbase;
    __half* h     = (__half*)hbase;

    const int NB = (KB + 1023) / 1024;
    const int gb_mm = (N + 63) / 64;
    const int gb_ag = (N + 3) / 4;

    // CSR build: zero global atomics (histA also preps Wt1/Wt2 on block 0)
    k_histA<<<PART_BLOCKS, 256, 0, stream>>>(col, E, CH, K, bh, W1, W2, Wt1, Wt2);
    k_scan_partial<<<NB, TPB, 0, stream>>>(bh, bsums, KB);
    k_scan_final2<<<NB, TPB, 0, stream>>>(bh, bsums, bhs, KB, NB);
    k_partB<<<PART_BLOCKS, 256, 0, stream>>>(row, col, ew, bhs, E, CH, K, part2);
    k_csrC<<<K, 256, 0, stream>>>(part2, bhs, K, N, E, offs, cnt, dinv, csr);

    // layer 1
    k_matmul_mfma<128, true><<<gb_mm, 256, 0, stream>>>(x, Wt1, dinv, h, N);
    k_aggregate<<<gb_ag, 256, 0, stream>>>((const __half2*)h, offs, cnt, csr, dinv, b1,
                                           (__half2*)o, N);
    // layer 2
    k_matmul_mfma<64, false><<<gb_mm, 256, 0, stream>>>(o, Wt2, dinv, h, N);
    k_aggregate<<<gb_ag, 256, 0, stream>>>((const __half2*)h, offs, cnt, csr, dinv, b2,
                                           (__half2*)o, N);
    // pool + head
    k_pool4<<<G * 4, 256, 0, stream>>>(o, bat, N, psum);
    k_head<<<G, 64, 0, stream>>>(psum, bat, N, Wc1, bc1, Wc2, bc2, out);
}